// Round 3
// baseline (1398.243 us; speedup 1.0000x reference)
//
#include <hip/hip_runtime.h>

#define NSTR 8
#define DM 2048
#define NK 120
#define NKP 128

// ============================================================================
// PATH: mean8 (streaming) -> proj (split-K GEMM, no atomics) -> cayley
// ws layout: xa [npos][2048] f32 at offset 0; zp [npos][8][128] f32 after.
// ============================================================================

// ---------------- kernel A: xa = mean over 8 streams (pure streaming) --------
// One block per position. All 16 loads are issued before ANY arithmetic
// (independent dests -> 16 global_load_dwordx4 in flight per lane), then a
// tree reduction. Every load instruction: 64 contiguous lanes x 16 B = 1 KB.
__global__ __launch_bounds__(256)
void mean8(const float4* __restrict__ s4, float4* __restrict__ xa4, int pbase) {
    const int t = threadIdx.x;
    const size_t p = blockIdx.x;                       // local position
    const float4* src = s4 + (size_t)(pbase + p) * (NSTR * DM / 4) + t;
    float4 u[8], w[8];
#pragma unroll
    for (int n = 0; n < 8; ++n) u[n] = src[(size_t)n * (DM / 4)];
#pragma unroll
    for (int n = 0; n < 8; ++n) w[n] = src[(size_t)n * (DM / 4) + 256];
#pragma unroll
    for (int n = 0; n < 4; ++n) {
        u[n].x += u[n + 4].x; u[n].y += u[n + 4].y; u[n].z += u[n + 4].z; u[n].w += u[n + 4].w;
        w[n].x += w[n + 4].x; w[n].y += w[n + 4].y; w[n].z += w[n + 4].z; w[n].w += w[n + 4].w;
    }
#pragma unroll
    for (int n = 0; n < 2; ++n) {
        u[n].x += u[n + 2].x; u[n].y += u[n + 2].y; u[n].z += u[n + 2].z; u[n].w += u[n + 2].w;
        w[n].x += w[n + 2].x; w[n].y += w[n + 2].y; w[n].z += w[n + 2].z; w[n].w += w[n + 2].w;
    }
    u[0].x += u[1].x; u[0].y += u[1].y; u[0].z += u[1].z; u[0].w += u[1].w;
    w[0].x += w[1].x; w[0].y += w[1].y; w[0].z += w[1].z; w[0].w += w[1].w;
    u[0].x *= 0.125f; u[0].y *= 0.125f; u[0].z *= 0.125f; u[0].w *= 0.125f;
    w[0].x *= 0.125f; w[0].y *= 0.125f; w[0].z *= 0.125f; w[0].w *= 0.125f;
    xa4[p * (DM / 4) + t] = u[0];
    xa4[p * (DM / 4) + t + 256] = w[0];
}

// ---------------- kernel B: z-partials = xa * W^T (tiled fp32 GEMM) ----------
// grid = (npos/128) * 8 k-slices; block 256; 2 wg/CU (64 KB LDS).
// Double-buffered 32-d sub-tiles, ONE barrier per sub: after the barrier each
// wave issues next-sub global loads, computes buf[cur], then writes buf[cur^1]
// (vmcnt wait has the whole compute phase of slack). Swizzle: chunk ^= (row>>3)&7
// -> staging writes 2-way (free), a-reads broadcast, b-reads 2-way (free).
__global__ __launch_bounds__(256, 2)
void proj(const float* __restrict__ xa, const float* __restrict__ Wm,
          float* __restrict__ zp, int npos) {
    __shared__ float4 sxa[2][128 * 8];  // 2 x 16 KB: xa tile [128 p][32 d]
    __shared__ float4 sw[2][128 * 8];   // 2 x 16 KB: W  tile [128 k][32 d]

    const int t = threadIdx.x;
    const int slice = blockIdx.x & 7;   // 0..7  K-slice (256 d each)
    const int ptile = blockIdx.x >> 3;  // position tile
    const int pos0 = ptile * 128;
    const int typ = t >> 4;   // p-octet (compute)
    const int txk = t & 15;   // k-octet (compute)
    const int srow = t >> 3;  // staging row base (rows srow + 32*r)
    const int sc = t & 7;     // staging chunk

    float4 ra[4], rw[4];
    float acc[8][8];
#pragma unroll
    for (int i = 0; i < 8; ++i)
#pragma unroll
        for (int j = 0; j < 8; ++j) acc[i][j] = 0.f;

    auto loadr = [&](int sub) {
        const int d0 = slice * 256 + sub * 32 + sc * 4;
#pragma unroll
        for (int r = 0; r < 4; ++r) {
            const int row = srow + 32 * r;
            ra[r] = *(const float4*)(xa + (size_t)(pos0 + row) * DM + d0);
            rw[r] = (row < NK) ? *(const float4*)(Wm + (size_t)row * DM + d0)
                               : make_float4(0.f, 0.f, 0.f, 0.f);
        }
    };
    auto writeb = [&](int buf) {
#pragma unroll
        for (int r = 0; r < 4; ++r) {
            const int row = srow + 32 * r;
            const int cc = sc ^ (((srow >> 3) + 4 * r) & 7);
            sxa[buf][row * 8 + cc] = ra[r];
            sw[buf][row * 8 + cc] = rw[r];
        }
    };

    loadr(0);
    writeb(0);
    int cur = 0;

#pragma unroll 1
    for (int sub = 0; sub < 8; ++sub) {
        __syncthreads();              // buf[cur] fully written by all waves
        if (sub < 7) loadr(sub + 1);  // issue next-sub global loads early

        // ---- compute buf[cur]: 8 dq x (8 bcast a-reads + 8 b-reads + 256 fma)
#pragma unroll
        for (int dq = 0; dq < 8; ++dq) {
            float4 a[8];
#pragma unroll
            for (int i = 0; i < 8; ++i)
                a[i] = sxa[cur][(typ * 8 + i) * 8 + (dq ^ (typ & 7))];
#pragma unroll
            for (int j = 0; j < 8; ++j) {
                const float4 bv = sw[cur][(txk * 8 + j) * 8 + (dq ^ (txk & 7))];
#pragma unroll
                for (int i = 0; i < 8; ++i) {
                    acc[i][j] = fmaf(a[i].x, bv.x, acc[i][j]);
                    acc[i][j] = fmaf(a[i].y, bv.y, acc[i][j]);
                    acc[i][j] = fmaf(a[i].z, bv.z, acc[i][j]);
                    acc[i][j] = fmaf(a[i].w, bv.w, acc[i][j]);
                }
            }
        }

        if (sub < 7) writeb(cur ^ 1); // waits on its own loads; other buffer
        cur ^= 1;
    }

    // ---- store this slice's partial into [pos][slice][128] (no atomics) ----
#pragma unroll
    for (int i = 0; i < 8; ++i) {
        float* dst = zp + ((size_t)(pos0 + typ * 8 + i) * 8 + slice) * NKP + txk * 8;
        *(float4*)dst = make_float4(acc[i][0], acc[i][1], acc[i][2], acc[i][3]);
        *((float4*)dst + 1) = make_float4(acc[i][4], acc[i][5], acc[i][6], acc[i][7]);
    }
}

// ---------------- kernel C: Cayley transform + block-Frobenius ---------------
// One wave per position; 16x16 Gauss-Jordan in registers via shfl.
// zp layout [pos][NPARTS][NKP]: coalesced float4 loads + in-register slice
// reduction (+bvec), z-row parked in LDS.
template <int NPARTS>
__global__ __launch_bounds__(256)
void cayley_k(const float* __restrict__ zp, const float* __restrict__ bvec,
              float* __restrict__ out, int pbase) {
    __shared__ float zrow[4][NKP];
    const int t = threadIdx.x;
    const int wave = t >> 6;
    const int l = t & 63;
    const int pos = blockIdx.x * 4 + wave;   // local position
    const int j = l & 15;
    const int g = l >> 4;

    {
        const float4* src = (const float4*)(zp + (size_t)pos * NPARTS * NKP);
        float4 s = make_float4(0.f, 0.f, 0.f, 0.f);
#pragma unroll
        for (int q = 0; q < (NPARTS + 1) / 2; ++q) {
            const int idx = l + 64 * q;
            if (idx < NPARTS * 32) {
                const float4 v = src[idx];
                s.x += v.x; s.y += v.y; s.z += v.z; s.w += v.w;
            }
        }
        s.x += __shfl_xor(s.x, 32, 64);
        s.y += __shfl_xor(s.y, 32, 64);
        s.z += __shfl_xor(s.z, 32, 64);
        s.w += __shfl_xor(s.w, 32, 64);
        if (l < 32) {
            if (l < 30) {
                const float4 b4 = ((const float4*)bvec)[l];
                s.x += b4.x; s.y += b4.y; s.z += b4.z; s.w += b4.w;
            }
            ((float4*)&zrow[wave][0])[l] = s;
        }
    }
    __syncthreads();

    float m[4], x[4];
#pragma unroll
    for (int r = 0; r < 4; ++r) {
        const int i = 4 * r + g;
        float a;
        if (i < j) {
            a = zrow[wave][(i * (31 - i)) / 2 + (j - i - 1)];
        } else if (i > j) {
            a = -zrow[wave][(j * (31 - j)) / 2 + (i - j - 1)];
        } else {
            a = 0.f;
        }
        const float d = (i == j) ? 1.f : 0.f;
        m[r] = d + a;   // M = I + A
        x[r] = d - a;   // X = I - A
    }

#pragma unroll
    for (int k = 0; k < 16; ++k) {
        const int rr = k >> 2;
        const int src_row = (k & 3) << 4;
        const float mk  = __shfl(m[rr], src_row | j, 64);
        const float xk  = __shfl(x[rr], src_row | j, 64);
        const float mkk = __shfl(m[rr], src_row | k, 64);
        const float rk = 1.0f / mkk;
#pragma unroll
        for (int r = 0; r < 4; ++r) {
            const float mik = __shfl(m[r], (g << 4) | k, 64);
            const float f = (4 * r + g == k) ? 0.f : mik * rk;
            m[r] = fmaf(-f, mk, m[r]);
            x[r] = fmaf(-f, xk, x[r]);
        }
    }

    float h[4];
#pragma unroll
    for (int r = 0; r < 4; ++r) {
        const int i = 4 * r + g;
        const float mdiag = __shfl(m[r], (g << 4) | i, 64);
        const float q = x[r] / mdiag;
        float s = q * q;
        s += __shfl_xor(s, 1, 64);
        s += __shfl_xor(s, 16, 64);
        h[r] = s * 0.5f;
    }
    if (((j & 1) == 0) && ((g & 1) == 0)) {
        const int col = j >> 1;
#pragma unroll
        for (int r = 0; r < 4; ++r) {
            const int row = 2 * r + (g >> 1);
            out[(size_t)(pbase + pos) * 64 + row * 8 + col] = h[r];
        }
    }
}

// ============================================================================
// FALLBACK PATH (workspace too small): fused mean+proj with atomics into a
// single z buffer [pos][1][128], then cayley_k<1>.
// ============================================================================
#define TM 128
#define DSLICE 256
#define SD 64

__global__ void zero_ws(float4* z4) {
    z4[(size_t)blockIdx.x * 256 + threadIdx.x] = make_float4(0.f, 0.f, 0.f, 0.f);
}

__global__ __launch_bounds__(256, 2)
void mean_proj_fused(const float* __restrict__ streams, const float* __restrict__ W,
                     float* __restrict__ z) {
    __shared__ float4 sxa[TM * 16];
    __shared__ float4 sw[NKP * 16];

    const int t = threadIdx.x;
    const int bid = blockIdx.x;
    const int slice = bid >> 6;
    const int ptile = bid & 63;
    const int pos0 = ptile * TM;
    const int typ = t >> 4;
    const int txk = t & 15;

    float acc[8][8];
#pragma unroll
    for (int i = 0; i < 8; ++i)
#pragma unroll
        for (int j = 0; j < 8; ++j) acc[i][j] = 0.f;

    for (int sub = 0; sub < 4; ++sub) {
        const int ds0 = slice * DSLICE + sub * SD;
#pragma unroll
        for (int r = 0; r < 8; ++r) {
            const int item = t + 256 * r;
            const int p = item >> 4;
            const int dq = item & 15;
            const float4* src = (const float4*)(streams
                + (size_t)(pos0 + p) * NSTR * DM + ds0 + dq * 4);
            float4 v = src[0];
#pragma unroll
            for (int n = 1; n < 8; ++n) {
                const float4 u = src[n * (DM / 4)];
                v.x += u.x; v.y += u.y; v.z += u.z; v.w += u.w;
            }
            v.x *= 0.125f; v.y *= 0.125f; v.z *= 0.125f; v.w *= 0.125f;
            sxa[p * 16 + (dq ^ (p >> 3))] = v;
        }
#pragma unroll
        for (int r = 0; r < 8; ++r) {
            const int item = t + 256 * r;
            const int k = item >> 4;
            const int dq = item & 15;
            float4 v = make_float4(0.f, 0.f, 0.f, 0.f);
            if (k < NK) v = *(const float4*)(W + (size_t)k * DM + ds0 + dq * 4);
            sw[k * 16 + (dq ^ (k >> 3))] = v;
        }
        __syncthreads();

        for (int dq = 0; dq < 16; ++dq) {
            float4 a[8];
#pragma unroll
            for (int i = 0; i < 8; ++i) a[i] = sxa[(typ * 8 + i) * 16 + (dq ^ typ)];
#pragma unroll
            for (int j = 0; j < 8; ++j) {
                const float4 bv = sw[(txk * 8 + j) * 16 + (dq ^ txk)];
#pragma unroll
                for (int i = 0; i < 8; ++i) {
                    acc[i][j] = fmaf(a[i].x, bv.x, acc[i][j]);
                    acc[i][j] = fmaf(a[i].y, bv.y, acc[i][j]);
                    acc[i][j] = fmaf(a[i].z, bv.z, acc[i][j]);
                    acc[i][j] = fmaf(a[i].w, bv.w, acc[i][j]);
                }
            }
        }
        __syncthreads();
    }

#pragma unroll
    for (int i = 0; i < 8; ++i) {
        const size_t p = (size_t)pos0 + typ * 8 + i;
#pragma unroll
        for (int j = 0; j < 8; ++j) {
            const int k = txk * 8 + j;
            if (k < NK) atomicAdd(&z[p * NKP + k], acc[i][j]);
        }
    }
}

// ---------------- launcher ---------------------------------------------------
extern "C" void kernel_launch(void* const* d_in, const int* in_sizes, int n_in,
                              void* d_out, int out_size, void* d_ws, size_t ws_size,
                              hipStream_t stream) {
    const float* streams = (const float*)d_in[0];  // [2,4096,8,2048] fp32
    const float* W       = (const float*)d_in[1];  // [120,2048] fp32
    const float* bvec    = (const float*)d_in[2];  // [120] fp32
    float* out = (float*)d_out;                    // [2,4096,8,8] fp32

    const size_t TOTPOS = 8192;
    const size_t XA_FULL = TOTPOS * DM * sizeof(float);          // 64 MiB
    const size_t ZP_FULL = 8 * TOTPOS * NKP * sizeof(float);     // 32 MiB

    int nb = 0;
    size_t npos = 0;
    if (ws_size >= XA_FULL + ZP_FULL)               { nb = 1; npos = 8192; }
    else if (ws_size >= (XA_FULL + ZP_FULL) / 2)    { nb = 2; npos = 4096; }

    if (nb > 0) {
        float* xa = (float*)d_ws;
        float* zp = (float*)((char*)d_ws + npos * DM * sizeof(float));
        for (int b = 0; b < nb; ++b) {
            const int pbase = (int)(b * npos);
            mean8<<<(int)npos, 256, 0, stream>>>(
                (const float4*)streams, (float4*)xa, pbase);
            proj<<<(int)((npos / 128) * 8), 256, 0, stream>>>(xa, W, zp, (int)npos);
            cayley_k<8><<<(int)(npos / 4), 256, 0, stream>>>(zp, bvec, out, pbase);
        }
    } else {
        // fallback: fused path (needs only 4 MiB ws)
        float* z = (float*)d_ws;
        zero_ws<<<1024, 256, 0, stream>>>((float4*)d_ws);
        mean_proj_fused<<<512, 256, 0, stream>>>(streams, W, z);
        cayley_k<1><<<2048, 256, 0, stream>>>(z, bvec, out, 0);
    }
}

// Round 4
// 775.699 us; speedup vs baseline: 1.8026x; 1.8026x over previous
//
#include <hip/hip_runtime.h>

#define NSTR 8
#define DM 2048
#define NK 120
#define NKP 128
#define NSLC 16   // split-K slices (128 d each)

// ============================================================================
// PATH: mean8 (streaming) -> proj (split-K GEMM, no atomics) -> cayley
// ws layout: xa [npos][2048] f32 at offset 0; zp [npos][16][128] f32 after.
// ============================================================================

// ---------------- kernel A: xa = mean over 8 streams (pure streaming) --------
// One block per position. All 16 loads issued before any arithmetic
// (independent dests -> 16 global_load_dwordx4 in flight), then tree-reduce.
__global__ __launch_bounds__(256)
void mean8(const float4* __restrict__ s4, float4* __restrict__ xa4, int pbase) {
    const int t = threadIdx.x;
    const size_t p = blockIdx.x;
    const float4* src = s4 + (size_t)(pbase + p) * (NSTR * DM / 4) + t;
    float4 u[8], w[8];
#pragma unroll
    for (int n = 0; n < 8; ++n) u[n] = src[(size_t)n * (DM / 4)];
#pragma unroll
    for (int n = 0; n < 8; ++n) w[n] = src[(size_t)n * (DM / 4) + 256];
#pragma unroll
    for (int n = 0; n < 4; ++n) {
        u[n].x += u[n + 4].x; u[n].y += u[n + 4].y; u[n].z += u[n + 4].z; u[n].w += u[n + 4].w;
        w[n].x += w[n + 4].x; w[n].y += w[n + 4].y; w[n].z += w[n + 4].z; w[n].w += w[n + 4].w;
    }
#pragma unroll
    for (int n = 0; n < 2; ++n) {
        u[n].x += u[n + 2].x; u[n].y += u[n + 2].y; u[n].z += u[n + 2].z; u[n].w += u[n + 2].w;
        w[n].x += w[n + 2].x; w[n].y += w[n + 2].y; w[n].z += w[n + 2].z; w[n].w += w[n + 2].w;
    }
    u[0].x += u[1].x; u[0].y += u[1].y; u[0].z += u[1].z; u[0].w += u[1].w;
    w[0].x += w[1].x; w[0].y += w[1].y; w[0].z += w[1].z; w[0].w += w[1].w;
    u[0].x *= 0.125f; u[0].y *= 0.125f; u[0].z *= 0.125f; u[0].w *= 0.125f;
    w[0].x *= 0.125f; w[0].y *= 0.125f; w[0].z *= 0.125f; w[0].w *= 0.125f;
    xa4[p * (DM / 4) + t] = u[0];
    xa4[p * (DM / 4) + t + 256] = w[0];
}

// ---------------- kernel B: z-partials = xa * W^T (tiled fp32 GEMM) ----------
// grid = (npos/128) * 16 k-slices = 1024 -> 4 blocks/CU; 32 KB LDS/block.
// Single-buffered 32-d sub-tiles; staging is load->LDS-write (no long-lived
// prefetch registers -> live set ~105 fits the 128-VGPR cap of (256,4); the
// round-3 spill came from 165 live regs at the same cap).
// Latency hiding comes from 16 waves/CU across 4 independent blocks.
// Swizzle: LDS chunk = src_chunk ^ ((row>>3)&7); reads use dq ^ (octet&7):
// a-reads broadcast per 16 lanes, b-reads spread all 8 bank-groups.
__global__ __launch_bounds__(256, 4)
void proj(const float* __restrict__ xa, const float* __restrict__ Wm,
          float* __restrict__ zp, int npos) {
    __shared__ float4 sxa[128 * 8];  // 16 KB: xa tile [128 p][32 d]
    __shared__ float4 sw[128 * 8];   // 16 KB: W  tile [128 k][32 d]

    const int t = threadIdx.x;
    const int slice = blockIdx.x & 15;  // 0..15 K-slice (128 d each)
    const int ptile = blockIdx.x >> 4;  // position tile
    const int pos0 = ptile * 128;
    const int typ = t >> 4;   // p-octet (compute)
    const int txk = t & 15;   // k-octet (compute)

    float acc[8][8];
#pragma unroll
    for (int i = 0; i < 8; ++i)
#pragma unroll
        for (int j = 0; j < 8; ++j) acc[i][j] = 0.f;

#pragma unroll 1
    for (int sub = 0; sub < 4; ++sub) {
        const int d0 = slice * 128 + sub * 32;

        // ---- stage A tile: 4 chunk-slots per thread ----
#pragma unroll
        for (int r = 0; r < 4; ++r) {
            const int s = t + 256 * r;
            const int row = s >> 3;
            const int cc = s & 7;
            sxa[row * 8 + (cc ^ ((row >> 3) & 7))] =
                *(const float4*)(xa + (size_t)(pos0 + row) * DM + d0 + cc * 4);
        }
        // ---- stage B tile (rows 120..127 zero) ----
#pragma unroll
        for (int r = 0; r < 4; ++r) {
            const int s = t + 256 * r;
            const int row = s >> 3;
            const int cc = s & 7;
            float4 v = make_float4(0.f, 0.f, 0.f, 0.f);
            if (row < NK) v = *(const float4*)(Wm + (size_t)row * DM + d0 + cc * 4);
            sw[row * 8 + (cc ^ ((row >> 3) & 7))] = v;
        }
        __syncthreads();

        // ---- GEMM micro-tile: per d-quad, 16 b128 LDS reads feed 256 fmac ----
        for (int dq = 0; dq < 8; ++dq) {
            float4 a[8];
#pragma unroll
            for (int i = 0; i < 8; ++i)
                a[i] = sxa[(typ * 8 + i) * 8 + (dq ^ (typ & 7))];
#pragma unroll
            for (int j = 0; j < 8; ++j) {
                const float4 bv = sw[(txk * 8 + j) * 8 + (dq ^ (txk & 7))];
#pragma unroll
                for (int i = 0; i < 8; ++i) {
                    acc[i][j] = fmaf(a[i].x, bv.x, acc[i][j]);
                    acc[i][j] = fmaf(a[i].y, bv.y, acc[i][j]);
                    acc[i][j] = fmaf(a[i].z, bv.z, acc[i][j]);
                    acc[i][j] = fmaf(a[i].w, bv.w, acc[i][j]);
                }
            }
        }
        __syncthreads();
    }

    // ---- store this slice's partial into [pos][slice][128] (no atomics) ----
#pragma unroll
    for (int i = 0; i < 8; ++i) {
        float* dst = zp + ((size_t)(pos0 + typ * 8 + i) * NSLC + slice) * NKP + txk * 8;
        *(float4*)dst = make_float4(acc[i][0], acc[i][1], acc[i][2], acc[i][3]);
        *((float4*)dst + 1) = make_float4(acc[i][4], acc[i][5], acc[i][6], acc[i][7]);
    }
}

// ---------------- kernel C: Cayley transform + block-Frobenius ---------------
// One wave per position; 16x16 Gauss-Jordan in registers via shfl.
// zp layout [pos][NPARTS][NKP]: coalesced float4 loads + in-register slice
// reduction (+bvec), z-row parked in LDS.
template <int NPARTS>
__global__ __launch_bounds__(256)
void cayley_k(const float* __restrict__ zp, const float* __restrict__ bvec,
              float* __restrict__ out, int pbase) {
    __shared__ float zrow[4][NKP];
    const int t = threadIdx.x;
    const int wave = t >> 6;
    const int l = t & 63;
    const int pos = blockIdx.x * 4 + wave;
    const int j = l & 15;
    const int g = l >> 4;

    {
        const float4* src = (const float4*)(zp + (size_t)pos * NPARTS * NKP);
        float4 s = make_float4(0.f, 0.f, 0.f, 0.f);
#pragma unroll
        for (int q = 0; q < (NPARTS + 1) / 2; ++q) {
            const int idx = l + 64 * q;
            if (idx < NPARTS * 32) {
                const float4 v = src[idx];
                s.x += v.x; s.y += v.y; s.z += v.z; s.w += v.w;
            }
        }
        s.x += __shfl_xor(s.x, 32, 64);
        s.y += __shfl_xor(s.y, 32, 64);
        s.z += __shfl_xor(s.z, 32, 64);
        s.w += __shfl_xor(s.w, 32, 64);
        if (l < 32) {
            if (l < 30) {
                const float4 b4 = ((const float4*)bvec)[l];
                s.x += b4.x; s.y += b4.y; s.z += b4.z; s.w += b4.w;
            }
            ((float4*)&zrow[wave][0])[l] = s;
        }
    }
    __syncthreads();

    float m[4], x[4];
#pragma unroll
    for (int r = 0; r < 4; ++r) {
        const int i = 4 * r + g;
        float a;
        if (i < j) {
            a = zrow[wave][(i * (31 - i)) / 2 + (j - i - 1)];
        } else if (i > j) {
            a = -zrow[wave][(j * (31 - j)) / 2 + (i - j - 1)];
        } else {
            a = 0.f;
        }
        const float d = (i == j) ? 1.f : 0.f;
        m[r] = d + a;   // M = I + A
        x[r] = d - a;   // X = I - A
    }

#pragma unroll
    for (int k = 0; k < 16; ++k) {
        const int rr = k >> 2;
        const int src_row = (k & 3) << 4;
        const float mk  = __shfl(m[rr], src_row | j, 64);
        const float xk  = __shfl(x[rr], src_row | j, 64);
        const float mkk = __shfl(m[rr], src_row | k, 64);
        const float rk = 1.0f / mkk;
#pragma unroll
        for (int r = 0; r < 4; ++r) {
            const float mik = __shfl(m[r], (g << 4) | k, 64);
            const float f = (4 * r + g == k) ? 0.f : mik * rk;
            m[r] = fmaf(-f, mk, m[r]);
            x[r] = fmaf(-f, xk, x[r]);
        }
    }

    float h[4];
#pragma unroll
    for (int r = 0; r < 4; ++r) {
        const int i = 4 * r + g;
        const float mdiag = __shfl(m[r], (g << 4) | i, 64);
        const float q = x[r] / mdiag;
        float s = q * q;
        s += __shfl_xor(s, 1, 64);
        s += __shfl_xor(s, 16, 64);
        h[r] = s * 0.5f;
    }
    if (((j & 1) == 0) && ((g & 1) == 0)) {
        const int col = j >> 1;
#pragma unroll
        for (int r = 0; r < 4; ++r) {
            const int row = 2 * r + (g >> 1);
            out[(size_t)(pbase + pos) * 64 + row * 8 + col] = h[r];
        }
    }
}

// ============================================================================
// FALLBACK PATH (workspace too small): fused mean+proj with atomics into a
// single z buffer [pos][1][128], then cayley_k<1>.
// ============================================================================
#define TM 128
#define DSLICE 256
#define SD 64

__global__ void zero_ws(float4* z4) {
    z4[(size_t)blockIdx.x * 256 + threadIdx.x] = make_float4(0.f, 0.f, 0.f, 0.f);
}

__global__ __launch_bounds__(256, 2)
void mean_proj_fused(const float* __restrict__ streams, const float* __restrict__ W,
                     float* __restrict__ z) {
    __shared__ float4 sxa[TM * 16];
    __shared__ float4 sw[NKP * 16];

    const int t = threadIdx.x;
    const int bid = blockIdx.x;
    const int slice = bid >> 6;
    const int ptile = bid & 63;
    const int pos0 = ptile * TM;
    const int typ = t >> 4;
    const int txk = t & 15;

    float acc[8][8];
#pragma unroll
    for (int i = 0; i < 8; ++i)
#pragma unroll
        for (int j = 0; j < 8; ++j) acc[i][j] = 0.f;

    for (int sub = 0; sub < 4; ++sub) {
        const int ds0 = slice * DSLICE + sub * SD;
#pragma unroll
        for (int r = 0; r < 8; ++r) {
            const int item = t + 256 * r;
            const int p = item >> 4;
            const int dq = item & 15;
            const float4* src = (const float4*)(streams
                + (size_t)(pos0 + p) * NSTR * DM + ds0 + dq * 4);
            float4 v = src[0];
#pragma unroll
            for (int n = 1; n < 8; ++n) {
                const float4 u = src[n * (DM / 4)];
                v.x += u.x; v.y += u.y; v.z += u.z; v.w += u.w;
            }
            v.x *= 0.125f; v.y *= 0.125f; v.z *= 0.125f; v.w *= 0.125f;
            sxa[p * 16 + (dq ^ (p >> 3))] = v;
        }
#pragma unroll
        for (int r = 0; r < 8; ++r) {
            const int item = t + 256 * r;
            const int k = item >> 4;
            const int dq = item & 15;
            float4 v = make_float4(0.f, 0.f, 0.f, 0.f);
            if (k < NK) v = *(const float4*)(W + (size_t)k * DM + ds0 + dq * 4);
            sw[k * 16 + (dq ^ (k >> 3))] = v;
        }
        __syncthreads();

        for (int dq = 0; dq < 16; ++dq) {
            float4 a[8];
#pragma unroll
            for (int i = 0; i < 8; ++i) a[i] = sxa[(typ * 8 + i) * 16 + (dq ^ typ)];
#pragma unroll
            for (int j = 0; j < 8; ++j) {
                const float4 bv = sw[(txk * 8 + j) * 16 + (dq ^ txk)];
#pragma unroll
                for (int i = 0; i < 8; ++i) {
                    acc[i][j] = fmaf(a[i].x, bv.x, acc[i][j]);
                    acc[i][j] = fmaf(a[i].y, bv.y, acc[i][j]);
                    acc[i][j] = fmaf(a[i].z, bv.z, acc[i][j]);
                    acc[i][j] = fmaf(a[i].w, bv.w, acc[i][j]);
                }
            }
        }
        __syncthreads();
    }

#pragma unroll
    for (int i = 0; i < 8; ++i) {
        const size_t p = (size_t)pos0 + typ * 8 + i;
#pragma unroll
        for (int j = 0; j < 8; ++j) {
            const int k = txk * 8 + j;
            if (k < NK) atomicAdd(&z[p * NKP + k], acc[i][j]);
        }
    }
}

// ---------------- launcher ---------------------------------------------------
extern "C" void kernel_launch(void* const* d_in, const int* in_sizes, int n_in,
                              void* d_out, int out_size, void* d_ws, size_t ws_size,
                              hipStream_t stream) {
    const float* streams = (const float*)d_in[0];  // [2,4096,8,2048] fp32
    const float* W       = (const float*)d_in[1];  // [120,2048] fp32
    const float* bvec    = (const float*)d_in[2];  // [120] fp32
    float* out = (float*)d_out;                    // [2,4096,8,8] fp32

    const size_t TOTPOS = 8192;
    const size_t XA_FULL = TOTPOS * DM * sizeof(float);           // 64 MiB
    const size_t ZP_FULL = NSLC * TOTPOS * NKP * sizeof(float);   // 64 MiB

    int nb = 0;
    size_t npos = 0;
    if (ws_size >= XA_FULL + ZP_FULL)               { nb = 1; npos = 8192; }
    else if (ws_size >= (XA_FULL + ZP_FULL) / 2)    { nb = 2; npos = 4096; }

    if (nb > 0) {
        float* xa = (float*)d_ws;
        float* zp = (float*)((char*)d_ws + npos * DM * sizeof(float));
        for (int b = 0; b < nb; ++b) {
            const int pbase = (int)(b * npos);
            mean8<<<(int)npos, 256, 0, stream>>>(
                (const float4*)streams, (float4*)xa, pbase);
            proj<<<(int)((npos / 128) * NSLC), 256, 0, stream>>>(xa, W, zp, (int)npos);
            cayley_k<NSLC><<<(int)(npos / 4), 256, 0, stream>>>(zp, bvec, out, pbase);
        }
    } else {
        // fallback: fused path (needs only 4 MiB ws)
        float* z = (float*)d_ws;
        zero_ws<<<1024, 256, 0, stream>>>((float4*)d_ws);
        mean_proj_fused<<<512, 256, 0, stream>>>(streams, W, z);
        cayley_k<1><<<2048, 256, 0, stream>>>(z, bvec, out, 0);
    }
}

// Round 5
// 730.369 us; speedup vs baseline: 1.9144x; 1.0621x over previous
//
#include <hip/hip_runtime.h>

#define NSTR 8
#define DM 2048
#define NK 120
#define NKP 128
#define NSLC 16   // split-K slices (128 d each)

// ============================================================================
// PATH: meanproj (fused streaming mean + split-K GEMM, no atomics) -> cayley
// ws layout: zp [npos][16][128] f32.
// Split-K partitions d, so the fused kernel reads each streams byte exactly
// once (slice s reads d in [128s,128s+128)) -- the 64 MiB xa round-trip and
// one kernel launch are eliminated; stream reads overlap GEMM compute.
// ============================================================================

// ---------------- kernel B: zp = mean8(streams) * W^T --------------------
// grid = (npos/128) * 16 k-slices = 1024 -> 4 blocks/CU; 32 KB LDS/block.
// Per 32-d sub: stage W tile (4 loads), stage A tile = on-the-fly mean of 8
// streams (4 slots x [8 independent loads + tree reduce], slot loop kept
// rolled so live set ~106 regs fits the 128-VGPR cap -- round-3 lesson).
// Natural bid mapping puts all ptiles of one slice on one XCD (bid%8 =
// slice%8) -> the slice's 60 KB W-chunk stays L2-resident.
// Swizzle: LDS chunk = cc ^ ((row>>3)&7); a-reads broadcast, b-reads spread.
__global__ __launch_bounds__(256, 4)
void meanproj(const float* __restrict__ streams, const float* __restrict__ Wm,
              float* __restrict__ zp, int pbase) {
    __shared__ float4 sxa[128 * 8];  // 16 KB: mean tile [128 p][32 d]
    __shared__ float4 sw[128 * 8];   // 16 KB: W tile    [128 k][32 d]

    const int t = threadIdx.x;
    const int slice = blockIdx.x & 15;  // 0..15 K-slice (128 d each)
    const int ptile = blockIdx.x >> 4;  // position tile
    const int pos0 = ptile * 128;
    const int typ = t >> 4;   // p-octet (compute)
    const int txk = t & 15;   // k-octet (compute)

    float acc[8][8];
#pragma unroll
    for (int i = 0; i < 8; ++i)
#pragma unroll
        for (int j = 0; j < 8; ++j) acc[i][j] = 0.f;

#pragma unroll 1
    for (int sub = 0; sub < 4; ++sub) {
        const int d0 = slice * 128 + sub * 32;

        // ---- stage W tile (rows 120..127 zero): 4 transient loads ----
#pragma unroll
        for (int r = 0; r < 4; ++r) {
            const int s = t + 256 * r;
            const int row = s >> 3;
            const int cc = s & 7;
            float4 v = make_float4(0.f, 0.f, 0.f, 0.f);
            if (row < NK) v = *(const float4*)(Wm + (size_t)row * DM + d0 + cc * 4);
            sw[row * 8 + (cc ^ ((row >> 3) & 7))] = v;
        }

        // ---- stage A tile: mean over 8 streams, one slot at a time ----
#pragma unroll 1
        for (int r = 0; r < 4; ++r) {
            const int s = t + 256 * r;
            const int row = s >> 3;       // 0..127 position within tile
            const int cc = s & 7;         // 0..7 d-chunk
            const float4* src = (const float4*)(streams
                + (size_t)(pbase + pos0 + row) * NSTR * DM + d0 + cc * 4);
            float4 u[8];
#pragma unroll
            for (int n = 0; n < 8; ++n) u[n] = src[(size_t)n * (DM / 4)];
#pragma unroll
            for (int n = 0; n < 4; ++n) {
                u[n].x += u[n + 4].x; u[n].y += u[n + 4].y;
                u[n].z += u[n + 4].z; u[n].w += u[n + 4].w;
            }
            u[0].x += u[2].x; u[0].y += u[2].y; u[0].z += u[2].z; u[0].w += u[2].w;
            u[1].x += u[3].x; u[1].y += u[3].y; u[1].z += u[3].z; u[1].w += u[3].w;
            u[0].x += u[1].x; u[0].y += u[1].y; u[0].z += u[1].z; u[0].w += u[1].w;
            u[0].x *= 0.125f; u[0].y *= 0.125f; u[0].z *= 0.125f; u[0].w *= 0.125f;
            sxa[row * 8 + (cc ^ ((row >> 3) & 7))] = u[0];
        }
        __syncthreads();

        // ---- GEMM micro-tile: per d-quad, 16 b128 LDS reads feed 256 fmac ----
        for (int dq = 0; dq < 8; ++dq) {
            float4 a[8];
#pragma unroll
            for (int i = 0; i < 8; ++i)
                a[i] = sxa[(typ * 8 + i) * 8 + (dq ^ (typ & 7))];
#pragma unroll
            for (int j = 0; j < 8; ++j) {
                const float4 bv = sw[(txk * 8 + j) * 8 + (dq ^ (txk & 7))];
#pragma unroll
                for (int i = 0; i < 8; ++i) {
                    acc[i][j] = fmaf(a[i].x, bv.x, acc[i][j]);
                    acc[i][j] = fmaf(a[i].y, bv.y, acc[i][j]);
                    acc[i][j] = fmaf(a[i].z, bv.z, acc[i][j]);
                    acc[i][j] = fmaf(a[i].w, bv.w, acc[i][j]);
                }
            }
        }
        __syncthreads();
    }

    // ---- store this slice's partial into [pos][slice][128] (no atomics) ----
#pragma unroll
    for (int i = 0; i < 8; ++i) {
        float* dst = zp + ((size_t)(pos0 + typ * 8 + i) * NSLC + slice) * NKP + txk * 8;
        *(float4*)dst = make_float4(acc[i][0], acc[i][1], acc[i][2], acc[i][3]);
        *((float4*)dst + 1) = make_float4(acc[i][4], acc[i][5], acc[i][6], acc[i][7]);
    }
}

// ---------------- kernel C: Cayley transform + block-Frobenius ---------------
// One wave per position; 16x16 Gauss-Jordan in registers via shfl.
// zp layout [pos][NPARTS][NKP]: coalesced float4 loads + in-register slice
// reduction (+bvec), z-row parked in LDS.
template <int NPARTS>
__global__ __launch_bounds__(256)
void cayley_k(const float* __restrict__ zp, const float* __restrict__ bvec,
              float* __restrict__ out, int pbase) {
    __shared__ float zrow[4][NKP];
    const int t = threadIdx.x;
    const int wave = t >> 6;
    const int l = t & 63;
    const int pos = blockIdx.x * 4 + wave;
    const int j = l & 15;
    const int g = l >> 4;

    {
        const float4* src = (const float4*)(zp + (size_t)pos * NPARTS * NKP);
        float4 s = make_float4(0.f, 0.f, 0.f, 0.f);
#pragma unroll
        for (int q = 0; q < (NPARTS + 1) / 2; ++q) {
            const int idx = l + 64 * q;
            if (idx < NPARTS * 32) {
                const float4 v = src[idx];
                s.x += v.x; s.y += v.y; s.z += v.z; s.w += v.w;
            }
        }
        s.x += __shfl_xor(s.x, 32, 64);
        s.y += __shfl_xor(s.y, 32, 64);
        s.z += __shfl_xor(s.z, 32, 64);
        s.w += __shfl_xor(s.w, 32, 64);
        if (l < 32) {
            if (l < 30) {
                const float4 b4 = ((const float4*)bvec)[l];
                s.x += b4.x; s.y += b4.y; s.z += b4.z; s.w += b4.w;
            }
            ((float4*)&zrow[wave][0])[l] = s;
        }
    }
    __syncthreads();

    float m[4], x[4];
#pragma unroll
    for (int r = 0; r < 4; ++r) {
        const int i = 4 * r + g;
        float a;
        if (i < j) {
            a = zrow[wave][(i * (31 - i)) / 2 + (j - i - 1)];
        } else if (i > j) {
            a = -zrow[wave][(j * (31 - j)) / 2 + (i - j - 1)];
        } else {
            a = 0.f;
        }
        const float d = (i == j) ? 1.f : 0.f;
        m[r] = d + a;   // M = I + A
        x[r] = d - a;   // X = I - A
    }

#pragma unroll
    for (int k = 0; k < 16; ++k) {
        const int rr = k >> 2;
        const int src_row = (k & 3) << 4;
        const float mk  = __shfl(m[rr], src_row | j, 64);
        const float xk  = __shfl(x[rr], src_row | j, 64);
        const float mkk = __shfl(m[rr], src_row | k, 64);
        const float rk = 1.0f / mkk;
#pragma unroll
        for (int r = 0; r < 4; ++r) {
            const float mik = __shfl(m[r], (g << 4) | k, 64);
            const float f = (4 * r + g == k) ? 0.f : mik * rk;
            m[r] = fmaf(-f, mk, m[r]);
            x[r] = fmaf(-f, xk, x[r]);
        }
    }

    float h[4];
#pragma unroll
    for (int r = 0; r < 4; ++r) {
        const int i = 4 * r + g;
        const float mdiag = __shfl(m[r], (g << 4) | i, 64);
        const float q = x[r] / mdiag;
        float s = q * q;
        s += __shfl_xor(s, 1, 64);
        s += __shfl_xor(s, 16, 64);
        h[r] = s * 0.5f;
    }
    if (((j & 1) == 0) && ((g & 1) == 0)) {
        const int col = j >> 1;
#pragma unroll
        for (int r = 0; r < 4; ++r) {
            const int row = 2 * r + (g >> 1);
            out[(size_t)(pbase + pos) * 64 + row * 8 + col] = h[r];
        }
    }
}

// ============================================================================
// FALLBACK PATH (workspace too small): fused mean+proj with atomics into a
// single z buffer [pos][1][128], then cayley_k<1>. Needs only 4 MiB.
// ============================================================================
#define TM 128
#define DSLICE 256
#define SD 64

__global__ void zero_ws(float4* z4) {
    z4[(size_t)blockIdx.x * 256 + threadIdx.x] = make_float4(0.f, 0.f, 0.f, 0.f);
}

__global__ __launch_bounds__(256, 2)
void mean_proj_fused(const float* __restrict__ streams, const float* __restrict__ W,
                     float* __restrict__ z) {
    __shared__ float4 sxa[TM * 16];
    __shared__ float4 sw[NKP * 16];

    const int t = threadIdx.x;
    const int bid = blockIdx.x;
    const int slice = bid >> 6;
    const int ptile = bid & 63;
    const int pos0 = ptile * TM;
    const int typ = t >> 4;
    const int txk = t & 15;

    float acc[8][8];
#pragma unroll
    for (int i = 0; i < 8; ++i)
#pragma unroll
        for (int j = 0; j < 8; ++j) acc[i][j] = 0.f;

    for (int sub = 0; sub < 4; ++sub) {
        const int ds0 = slice * DSLICE + sub * SD;
#pragma unroll
        for (int r = 0; r < 8; ++r) {
            const int item = t + 256 * r;
            const int p = item >> 4;
            const int dq = item & 15;
            const float4* src = (const float4*)(streams
                + (size_t)(pos0 + p) * NSTR * DM + ds0 + dq * 4);
            float4 v = src[0];
#pragma unroll
            for (int n = 1; n < 8; ++n) {
                const float4 u = src[n * (DM / 4)];
                v.x += u.x; v.y += u.y; v.z += u.z; v.w += u.w;
            }
            v.x *= 0.125f; v.y *= 0.125f; v.z *= 0.125f; v.w *= 0.125f;
            sxa[p * 16 + (dq ^ (p >> 3))] = v;
        }
#pragma unroll
        for (int r = 0; r < 8; ++r) {
            const int item = t + 256 * r;
            const int k = item >> 4;
            const int dq = item & 15;
            float4 v = make_float4(0.f, 0.f, 0.f, 0.f);
            if (k < NK) v = *(const float4*)(W + (size_t)k * DM + ds0 + dq * 4);
            sw[k * 16 + (dq ^ (k >> 3))] = v;
        }
        __syncthreads();

        for (int dq = 0; dq < 16; ++dq) {
            float4 a[8];
#pragma unroll
            for (int i = 0; i < 8; ++i) a[i] = sxa[(typ * 8 + i) * 16 + (dq ^ typ)];
#pragma unroll
            for (int j = 0; j < 8; ++j) {
                const float4 bv = sw[(txk * 8 + j) * 16 + (dq ^ txk)];
#pragma unroll
                for (int i = 0; i < 8; ++i) {
                    acc[i][j] = fmaf(a[i].x, bv.x, acc[i][j]);
                    acc[i][j] = fmaf(a[i].y, bv.y, acc[i][j]);
                    acc[i][j] = fmaf(a[i].z, bv.z, acc[i][j]);
                    acc[i][j] = fmaf(a[i].w, bv.w, acc[i][j]);
                }
            }
        }
        __syncthreads();
    }

#pragma unroll
    for (int i = 0; i < 8; ++i) {
        const size_t p = (size_t)pos0 + typ * 8 + i;
#pragma unroll
        for (int j = 0; j < 8; ++j) {
            const int k = txk * 8 + j;
            if (k < NK) atomicAdd(&z[p * NKP + k], acc[i][j]);
        }
    }
}

// ---------------- launcher ---------------------------------------------------
extern "C" void kernel_launch(void* const* d_in, const int* in_sizes, int n_in,
                              void* d_out, int out_size, void* d_ws, size_t ws_size,
                              hipStream_t stream) {
    const float* streams = (const float*)d_in[0];  // [2,4096,8,2048] fp32
    const float* W       = (const float*)d_in[1];  // [120,2048] fp32
    const float* bvec    = (const float*)d_in[2];  // [120] fp32
    float* out = (float*)d_out;                    // [2,4096,8,8] fp32

    const size_t TOTPOS = 8192;
    const size_t ZP_FULL = NSLC * TOTPOS * NKP * sizeof(float);   // 64 MiB

    int nb = 0;
    size_t npos = 0;
    if (ws_size >= ZP_FULL)          { nb = 1; npos = 8192; }
    else if (ws_size >= ZP_FULL / 2) { nb = 2; npos = 4096; }

    if (nb > 0) {
        float* zp = (float*)d_ws;
        for (int b = 0; b < nb; ++b) {
            const int pbase = (int)(b * npos);
            meanproj<<<(int)((npos / 128) * NSLC), 256, 0, stream>>>(
                streams, W, zp, pbase);
            cayley_k<NSLC><<<(int)(npos / 4), 256, 0, stream>>>(zp, bvec, out, pbase);
        }
    } else {
        // fallback: atomic fused path (needs only 4 MiB ws)
        float* z = (float*)d_ws;
        zero_ws<<<1024, 256, 0, stream>>>((float4*)d_ws);
        mean_proj_fused<<<512, 256, 0, stream>>>(streams, W, z);
        cayley_k<1><<<2048, 256, 0, stream>>>(z, bvec, out, 0);
    }
}